// Round 1
// baseline (509.504 us; speedup 1.0000x reference)
//
#include <hip/hip_runtime.h>
#include <hip/hip_bf16.h>
#include <math.h>

// Problem constants
#define BQ   4096
#define D    256
#define NH   8
#define HD   32
#define LN_  64     // neighbors per node
#define DFF  1024
#define EPSV 1e-5f

// ---------------- helpers ----------------
__device__ __forceinline__ float wave_sum(float v){
#pragma unroll
  for (int off = 32; off; off >>= 1) v += __shfl_xor(v, off, 64);
  return v;
}
__device__ __forceinline__ float wave_max(float v){
#pragma unroll
  for (int off = 32; off; off >>= 1) v = fmaxf(v, __shfl_xor(v, off, 64));
  return v;
}

// ---------------- mask dtype detection ----------------
// nei_mask is bool in the reference; device encoding is ambiguous.
// Scan first 262144 bytes (safe for u8/i32/f32 encodings of 262144 elems):
//   any 4-byte group == 0x3F800000 -> float32 (flag 2)
//   any group with upper-3-bytes nonzero -> packed bytes (flag 1)
//   else -> int32 0/1 (flag 0)
__global__ void k_detect(const unsigned int* __restrict__ m, int* __restrict__ flag){
  __shared__ int s_byte, s_f32;
  if (threadIdx.x == 0){ s_byte = 0; s_f32 = 0; }
  __syncthreads();
  int fb = 0, ff = 0;
  for (int i = threadIdx.x; i < 65536; i += 256){
    unsigned int v = m[i];
    if (v == 0x3F800000u) ff = 1;
    else if (v & 0xFFFFFF00u) fb = 1;
  }
  if (fb) s_byte = 1;
  if (ff) s_f32 = 1;
  __syncthreads();
  if (threadIdx.x == 0) flag[0] = s_f32 ? 2 : (s_byte ? 1 : 0);
}

// ---------------- gather query-node embeddings ----------------
__global__ __launch_bounds__(256) void k_gather(const int* __restrict__ batch,
                                                const float* __restrict__ emb,
                                                float* __restrict__ X){
  int gid = blockIdx.x * 256 + threadIdx.x;   // over BQ*D/4 float4
  int b = gid >> 6;                            // 64 float4 per row
  int c = gid & 63;
  float4 v = ((const float4*)(emb + (size_t)batch[b] * D))[c];
  ((float4*)(X + (size_t)b * D))[c] = v;
}

// ---------------- generic tiled fp32 GEMM ----------------
// C[M,N] = epi(A[M,K] @ B[K,N]); A,B,C row-major contiguous.
// EPI: 0 none, 1 (acc+bias)*scale, 2 acc+bias, 3 relu(acc+bias)
template<int BM, int BN, int BK, int TM, int TN, int EPI>
__global__ __launch_bounds__(256) void k_gemm(const float* __restrict__ A,
                                              const float* __restrict__ Bw,
                                              const float* __restrict__ bias,
                                              float* __restrict__ Cout,
                                              int M, int N, int K, float scale){
  constexpr int TX = BN / TN, TY = BM / TM;
  static_assert(TX * TY == 256, "thread tiling");
  __shared__ float As[BK][BM + 4];  // transposed A tile (pad vs bank conflicts)
  __shared__ float Bs[BK][BN + 4];
  const int tid = threadIdx.x;
  const int tx = tid % TX, ty = tid / TX;
  const int row0 = blockIdx.y * BM, col0 = blockIdx.x * BN;
  float acc[TM][TN];
#pragma unroll
  for (int i = 0; i < TM; i++)
#pragma unroll
    for (int j = 0; j < TN; j++) acc[i][j] = 0.f;

  constexpr int LA = (BM * BK) / 1024;
  constexpr int LB = (BN * BK) / 1024;
  constexpr int AFR = BK / 4;   // float4 per A-tile row
  constexpr int BFR = BN / 4;

  for (int k0 = 0; k0 < K; k0 += BK){
#pragma unroll
    for (int s = 0; s < LA; s++){
      int idx = tid + 256 * s;
      int r = idx / AFR, c4 = idx % AFR;
      float4 v = *(const float4*)(A + (size_t)(row0 + r) * K + k0 + 4 * c4);
      As[4 * c4 + 0][r] = v.x; As[4 * c4 + 1][r] = v.y;
      As[4 * c4 + 2][r] = v.z; As[4 * c4 + 3][r] = v.w;
    }
#pragma unroll
    for (int s = 0; s < LB; s++){
      int idx = tid + 256 * s;
      int r = idx / BFR, c4 = idx % BFR;
      *(float4*)&Bs[r][4 * c4] = *(const float4*)(Bw + (size_t)(k0 + r) * N + col0 + 4 * c4);
    }
    __syncthreads();
#pragma unroll
    for (int kk = 0; kk < BK; kk++){
      float a[TM], bf[TN];
      if constexpr (TM == 8){
        *(float4*)&a[0] = *(float4*)&As[kk][ty * TM];
        *(float4*)&a[4] = *(float4*)&As[kk][ty * TM + 4];
      } else {
        *(float4*)&a[0] = *(float4*)&As[kk][ty * TM];
      }
      if constexpr (TN == 4){
        *(float4*)&bf[0] = *(float4*)&Bs[kk][tx * TN];
      } else {
        float2 t2 = *(float2*)&Bs[kk][tx * TN];
        bf[0] = t2.x; bf[1] = t2.y;
      }
#pragma unroll
      for (int i = 0; i < TM; i++)
#pragma unroll
        for (int j = 0; j < TN; j++)
          acc[i][j] = fmaf(a[i], bf[j], acc[i][j]);
    }
    __syncthreads();
  }
#pragma unroll
  for (int i = 0; i < TM; i++){
    int row = row0 + ty * TM + i;
#pragma unroll
    for (int j = 0; j < TN; j++){
      int col = col0 + tx * TN + j;
      float v = acc[i][j];
      if (EPI >= 1) v += bias[col];
      if (EPI == 1) v *= scale;
      if (EPI == 3) v = fmaxf(v, 0.f);
      Cout[(size_t)row * N + col] = v;
    }
  }
}

// ---------------- P[b,h,d] = sum_t Wk[d, h*HD+t] * Q[b, h*HD+t] ----------------
// (bk dropped: per-(b,h)-constant score shift is softmax-invariant)
#define PNB 8
__global__ __launch_bounds__(256) void k_pmat(const float* __restrict__ Q,
                                              const float* __restrict__ Wk,
                                              float* __restrict__ P){
  __shared__ float Qs[PNB][D];
  const int b0 = blockIdx.x * PNB;
  const int tid = threadIdx.x;
  for (int s = 0; s < PNB * D / 4 / 256; s++){
    int idx = tid + 256 * s;           // float4 idx
    int r = idx >> 6, c = idx & 63;
    ((float4*)Qs[r])[c] = ((const float4*)(Q + (size_t)(b0 + r) * D))[c];
  }
  __syncthreads();
#pragma unroll
  for (int h = 0; h < NH; h++){
    const int d = tid;
    float acc[PNB];
#pragma unroll
    for (int bb = 0; bb < PNB; bb++) acc[bb] = 0.f;
    const float* wrow = Wk + (size_t)d * D + h * HD;
    float wreg[HD];
#pragma unroll
    for (int t4 = 0; t4 < HD / 4; t4++)
      *(float4*)&wreg[4 * t4] = *(const float4*)(wrow + 4 * t4);
#pragma unroll
    for (int t = 0; t < HD; t++){
      float w = wreg[t];
#pragma unroll
      for (int bb = 0; bb < PNB; bb++)
        acc[bb] = fmaf(Qs[bb][h * HD + t], w, acc[bb]);
    }
#pragma unroll
    for (int bb = 0; bb < PNB; bb++)
      P[(size_t)(b0 + bb) * (NH * D) + h * D + d] = acc[bb];
  }
}

// ---------------- attention core: scores -> softmax -> C[b,h,d] ----------------
// One block per query b. Wave w owns neighbors l = w*16 + i (rows register-resident,
// one float4 of the 256-dim row per lane). C may alias P (P fully staged to LDS first).
__global__ __launch_bounds__(256) void k_attn(const int* __restrict__ nei_idx,
                                              const void* __restrict__ nei_mask,
                                              const int* __restrict__ flagp,
                                              const float* __restrict__ emb,
                                              const float* __restrict__ P,
                                              float* __restrict__ C){
  const int b = blockIdx.x;
  const int tid = threadIdx.x;
  const int w = tid >> 6, lane = tid & 63;
  __shared__ float Pl[NH * D];       // 8 KB
  __shared__ float sc[NH][LN_];      // 2 KB  scores -> att
  __shared__ float cp[4][NH * D];    // 32 KB per-wave partial C
  __shared__ int   nid[LN_];
  __shared__ float mskv[LN_];

  const int mf = flagp[0];
  if (tid < LN_){
    nid[tid] = nei_idx[(size_t)b * LN_ + tid];
    bool m;
    if (mf == 1)      m = ((const unsigned char*)nei_mask)[(size_t)b * LN_ + tid] != 0;
    else if (mf == 2) m = ((const float*)nei_mask)[(size_t)b * LN_ + tid] != 0.f;
    else              m = ((const int*)nei_mask)[(size_t)b * LN_ + tid] != 0;
    mskv[tid] = m ? 1.f : 0.f;
  }
  for (int s = 0; s < 2; s++){
    int i4 = tid + 256 * s;
    ((float4*)Pl)[i4] = ((const float4*)(P + (size_t)b * (NH * D)))[i4];
  }
  __syncthreads();

  // phase 1: load 16 neighbor rows (1 float4/lane each), compute scores
  float4 ereg[16];
#pragma unroll
  for (int i = 0; i < 16; i++){
    int l = w * 16 + i;
    ereg[i] = ((const float4*)(emb + (size_t)nid[l] * D))[lane];
  }
#pragma unroll
  for (int i = 0; i < 16; i++){
    int l = w * 16 + i;
    float part[NH];
#pragma unroll
    for (int h = 0; h < NH; h++){
      float4 p4 = ((const float4*)(Pl + h * D))[lane];
      part[h] = ereg[i].x * p4.x + ereg[i].y * p4.y + ereg[i].z * p4.z + ereg[i].w * p4.w;
    }
#pragma unroll
    for (int h = 0; h < NH; h++){
      float r = wave_sum(part[h]);
      if (lane == 0) sc[h][l] = r;
    }
  }
  __syncthreads();

  // softmax over l per h (wave 0 only; lane = l)
  if (tid < 64){
    int l = tid;
    bool m = mskv[l] > 0.5f;
#pragma unroll
    for (int h = 0; h < NH; h++){
      float v = m ? -INFINITY : sc[h][l];
      float mx = wave_max(v);
      float e = __expf(v - mx);          // -inf -> 0
      float sm = wave_sum(e);
      sc[h][l] = e / sm;
    }
  }
  __syncthreads();

  // phase 2: C[b,h,:] = sum_l att * e_l (per-wave partial, then reduce)
  float4 acc[NH];
#pragma unroll
  for (int h = 0; h < NH; h++) acc[h] = make_float4(0.f, 0.f, 0.f, 0.f);
#pragma unroll
  for (int i = 0; i < 16; i++){
    int l = w * 16 + i;
#pragma unroll
    for (int h = 0; h < NH; h++){
      float a = sc[h][l];
      acc[h].x = fmaf(a, ereg[i].x, acc[h].x);
      acc[h].y = fmaf(a, ereg[i].y, acc[h].y);
      acc[h].z = fmaf(a, ereg[i].z, acc[h].z);
      acc[h].w = fmaf(a, ereg[i].w, acc[h].w);
    }
  }
#pragma unroll
  for (int h = 0; h < NH; h++)
    ((float4*)(cp[w] + h * D))[lane] = acc[h];
  __syncthreads();
  for (int s = 0; s < 2; s++){
    int i4 = tid + 256 * s;
    float4 v0 = ((float4*)cp[0])[i4];
    float4 v1 = ((float4*)cp[1])[i4];
    float4 v2 = ((float4*)cp[2])[i4];
    float4 v3 = ((float4*)cp[3])[i4];
    float4 o = make_float4(v0.x + v1.x + v2.x + v3.x, v0.y + v1.y + v2.y + v3.y,
                           v0.z + v1.z + v2.z + v3.z, v0.w + v1.w + v2.w + v3.w);
    ((float4*)(C + (size_t)b * (NH * D)))[i4] = o;
  }
}

// ---------------- attout[b, h*HD+t] = sum_d C[b,h,d]*Wv[d,h*HD+t] + bv ----------------
__global__ __launch_bounds__(256) void k_attout(const float* __restrict__ C,
                                                const float* __restrict__ Wv,
                                                const float* __restrict__ bv,
                                                float* __restrict__ AO){
  const int h = blockIdx.y;
  const int b0 = blockIdx.x * 32;
  __shared__ float Cs[32][D + 4];
  __shared__ float Ws[D][HD];
  const int tid = threadIdx.x;
  for (int s = 0; s < 8; s++){
    int idx = tid + 256 * s;          // float4 over 32*64
    int r = idx >> 6, c = idx & 63;
    *(float4*)&Cs[r][4 * c] = ((const float4*)(C + (size_t)(b0 + r) * (NH * D) + h * D))[c];
  }
  for (int s = 0; s < 8; s++){
    int idx = tid + 256 * s;          // float4 over 256*8
    int d = idx >> 3, c = idx & 7;
    *(float4*)&Ws[d][4 * c] = *(const float4*)(Wv + (size_t)d * D + h * HD + 4 * c);
  }
  __syncthreads();
  const int rr = tid >> 3;            // 0..31 rows
  const int tx = tid & 7;             // 0..7  -> 4 cols each
  float4 acc = make_float4(0.f, 0.f, 0.f, 0.f);
#pragma unroll 4
  for (int d = 0; d < D; d++){
    float c = Cs[rr][d];
    float4 wv4 = *(float4*)&Ws[d][4 * tx];
    acc.x = fmaf(c, wv4.x, acc.x);
    acc.y = fmaf(c, wv4.y, acc.y);
    acc.z = fmaf(c, wv4.z, acc.z);
    acc.w = fmaf(c, wv4.w, acc.w);
  }
  float4 bb = *(const float4*)(bv + h * HD + 4 * tx);
  acc.x += bb.x; acc.y += bb.y; acc.z += bb.z; acc.w += bb.w;
  ((float4*)(AO + (size_t)(b0 + rr) * D + h * HD))[tx] = acc;
}

// ---------------- LayerNorm(out = LN(A+B)) ----------------
__global__ __launch_bounds__(256) void k_ln(const float* __restrict__ A,
                                            const float* __restrict__ Bv,
                                            const float* __restrict__ w,
                                            const float* __restrict__ bi,
                                            float* __restrict__ out){
  const int row = blockIdx.x, tid = threadIdx.x;
  const int wv = tid >> 6, lane = tid & 63;
  __shared__ float red[8];
  float v = A[(size_t)row * D + tid] + Bv[(size_t)row * D + tid];
  float s = wave_sum(v);
  if (lane == 0) red[wv] = s;
  __syncthreads();
  float mu = (red[0] + red[1] + red[2] + red[3]) * (1.f / D);
  float d = v - mu;
  float s2 = wave_sum(d * d);
  if (lane == 0) red[4 + wv] = s2;
  __syncthreads();
  float var = (red[4] + red[5] + red[6] + red[7]) * (1.f / D);
  out[(size_t)row * D + tid] = d * rsqrtf(var + EPSV) * w[tid] + bi[tid];
}

// ---------------- launch ----------------
extern "C" void kernel_launch(void* const* d_in, const int* in_sizes, int n_in,
                              void* d_out, int out_size, void* d_ws, size_t ws_size,
                              hipStream_t stream){
  (void)in_sizes; (void)n_in; (void)out_size; (void)ws_size;
  const int*   batch    = (const int*)d_in[0];
  const int*   nei_idx  = (const int*)d_in[1];
  const void*  nei_mask = d_in[2];
  const float* emb      = (const float*)d_in[3];
  const float* Wq = (const float*)d_in[4];  const float* bq = (const float*)d_in[5];
  const float* Wk = (const float*)d_in[6];  /* bk (d_in[7]) dropped: softmax-invariant */
  const float* Wv = (const float*)d_in[8];  const float* bv = (const float*)d_in[9];
  const float* Wo = (const float*)d_in[10]; const float* bo = (const float*)d_in[11];
  const float* W1 = (const float*)d_in[12]; const float* b1 = (const float*)d_in[13];
  const float* W2 = (const float*)d_in[14]; const float* b2 = (const float*)d_in[15];
  const float* ln1w = (const float*)d_in[16]; const float* ln1b = (const float*)d_in[17];
  const float* ln2w = (const float*)d_in[18]; const float* ln2b = (const float*)d_in[19];

  float* ws = (float*)d_ws;
  float* X  = ws;                       // [B,D]      4 MB
  float* Qb = ws + (size_t)1 * 1048576; // [B,D]      4 MB   (later reused as AO)
  float* P  = ws + (size_t)2 * 1048576; // [B,H,D]   33.5 MB (later reused as C)
  float* Y  = ws + (size_t)10 * 1048576;// [B,D]
  float* S  = ws + (size_t)11 * 1048576;// [B,D]
  float* HH = ws + (size_t)12 * 1048576;// [B,DFF]   16 MB
  float* F  = ws + (size_t)16 * 1048576;// [B,D]
  int*   flag = (int*)(ws + (size_t)17 * 1048576);
  float* out = (float*)d_out;

  const float qscale = 0.17677669529663687f;  // HD^-0.5

  k_detect<<<1, 256, 0, stream>>>((const unsigned int*)nei_mask, flag);
  k_gather<<<BQ * D / 4 / 256, 256, 0, stream>>>(batch, emb, X);
  // Q = (X@Wq + bq) * scale
  k_gemm<64, 32, 32, 4, 2, 1><<<dim3(D / 32, BQ / 64), 256, 0, stream>>>(X, Wq, bq, Qb, BQ, D, D, qscale);
  k_pmat<<<BQ / PNB, 256, 0, stream>>>(Qb, Wk, P);
  k_attn<<<BQ, 256, 0, stream>>>(nei_idx, nei_mask, flag, emb, P, P /* C aliases P */);
  k_attout<<<dim3(BQ / 32, NH), 256, 0, stream>>>(P, Wv, bv, Qb /* AO aliases Q */);
  // Y = AO@Wo + bo
  k_gemm<64, 32, 32, 4, 2, 2><<<dim3(D / 32, BQ / 64), 256, 0, stream>>>(Qb, Wo, bo, Y, BQ, D, D, 1.f);
  k_ln<<<BQ, 256, 0, stream>>>(X, Y, ln1w, ln1b, S);
  // HH = relu(S@W1 + b1)
  k_gemm<128, 64, 32, 8, 4, 3><<<dim3(DFF / 64, BQ / 128), 256, 0, stream>>>(S, W1, b1, HH, BQ, DFF, D, 1.f);
  // F = relu(HH@W2 + b2)
  k_gemm<64, 32, 32, 4, 2, 3><<<dim3(D / 32, BQ / 64), 256, 0, stream>>>(HH, W2, b2, F, BQ, D, DFF, 1.f);
  k_ln<<<BQ, 256, 0, stream>>>(S, F, ln2w, ln2b, out);
}

// Round 2
// 291.386 us; speedup vs baseline: 1.7486x; 1.7486x over previous
//
#include <hip/hip_runtime.h>
#include <hip/hip_bf16.h>
#include <math.h>

// Problem constants
#define BQ   4096
#define D    256
#define NH   8
#define HD   32
#define LN_  64     // neighbors per node
#define DFF  1024
#define EPSV 1e-5f

typedef __attribute__((ext_vector_type(8))) short short8;
typedef __attribute__((ext_vector_type(4))) float f32x4;

// LDS XOR swizzle (G4): spread 512B-stride rows across banks; bijective, involution.
#define ESWZ(row, byte) ((byte) ^ (((row) & 7) << 4))

// ---------------- helpers ----------------
__device__ __forceinline__ float wave_sum(float v){
#pragma unroll
  for (int off = 32; off; off >>= 1) v += __shfl_xor(v, off, 64);
  return v;
}
__device__ __forceinline__ unsigned short f2bf(float f){
  unsigned int u = __float_as_uint(f);
  unsigned int r = (u + 0x7FFFu + ((u >> 16) & 1u)) >> 16;   // RNE
  return (unsigned short)r;
}

// ---------------- mask dtype detection ----------------
__global__ void k_detect(const unsigned int* __restrict__ m, int* __restrict__ flag){
  __shared__ int s_byte, s_f32;
  if (threadIdx.x == 0){ s_byte = 0; s_f32 = 0; }
  __syncthreads();
  int fb = 0, ff = 0;
  for (int i = threadIdx.x; i < 65536; i += 256){
    unsigned int v = m[i];
    if (v == 0x3F800000u) ff = 1;
    else if (v & 0xFFFFFF00u) fb = 1;
  }
  if (fb) s_byte = 1;
  if (ff) s_f32 = 1;
  __syncthreads();
  if (threadIdx.x == 0) flag[0] = s_f32 ? 2 : (s_byte ? 1 : 0);
}

// ---------------- gather query-node embeddings ----------------
__global__ __launch_bounds__(256) void k_gather(const int* __restrict__ batch,
                                                const float* __restrict__ emb,
                                                float* __restrict__ X){
  int gid = blockIdx.x * 256 + threadIdx.x;   // over BQ*D/4 float4
  int b = gid >> 6;
  int c = gid & 63;
  float4 v = ((const float4*)(emb + (size_t)batch[b] * D))[c];
  ((float4*)(X + (size_t)b * D))[c] = v;
}

// ---------------- generic tiled fp32 GEMM ----------------
// EPI: 0 none, 1 (acc+bias)*scale, 2 acc+bias, 3 relu(acc+bias)
template<int BM, int BN, int BK, int TM, int TN, int EPI>
__global__ __launch_bounds__(256) void k_gemm(const float* __restrict__ A,
                                              const float* __restrict__ Bw,
                                              const float* __restrict__ bias,
                                              float* __restrict__ Cout,
                                              int M, int N, int K, float scale){
  constexpr int TX = BN / TN, TY = BM / TM;
  static_assert(TX * TY == 256, "thread tiling");
  __shared__ float As[BK][BM + 4];
  __shared__ float Bs[BK][BN + 4];
  const int tid = threadIdx.x;
  const int tx = tid % TX, ty = tid / TX;
  const int row0 = blockIdx.y * BM, col0 = blockIdx.x * BN;
  float acc[TM][TN];
#pragma unroll
  for (int i = 0; i < TM; i++)
#pragma unroll
    for (int j = 0; j < TN; j++) acc[i][j] = 0.f;

  constexpr int LA = (BM * BK) / 1024;
  constexpr int LB = (BN * BK) / 1024;
  constexpr int AFR = BK / 4;
  constexpr int BFR = BN / 4;

  for (int k0 = 0; k0 < K; k0 += BK){
#pragma unroll
    for (int s = 0; s < LA; s++){
      int idx = tid + 256 * s;
      int r = idx / AFR, c4 = idx % AFR;
      float4 v = *(const float4*)(A + (size_t)(row0 + r) * K + k0 + 4 * c4);
      As[4 * c4 + 0][r] = v.x; As[4 * c4 + 1][r] = v.y;
      As[4 * c4 + 2][r] = v.z; As[4 * c4 + 3][r] = v.w;
    }
#pragma unroll
    for (int s = 0; s < LB; s++){
      int idx = tid + 256 * s;
      int r = idx / BFR, c4 = idx % BFR;
      *(float4*)&Bs[r][4 * c4] = *(const float4*)(Bw + (size_t)(k0 + r) * N + col0 + 4 * c4);
    }
    __syncthreads();
#pragma unroll
    for (int kk = 0; kk < BK; kk++){
      float a[TM], bf[TN];
      if constexpr (TM == 8){
        *(float4*)&a[0] = *(float4*)&As[kk][ty * TM];
        *(float4*)&a[4] = *(float4*)&As[kk][ty * TM + 4];
      } else {
        *(float4*)&a[0] = *(float4*)&As[kk][ty * TM];
      }
      if constexpr (TN == 4){
        *(float4*)&bf[0] = *(float4*)&Bs[kk][tx * TN];
      } else {
        float2 t2 = *(float2*)&Bs[kk][tx * TN];
        bf[0] = t2.x; bf[1] = t2.y;
      }
#pragma unroll
      for (int i = 0; i < TM; i++)
#pragma unroll
        for (int j = 0; j < TN; j++)
          acc[i][j] = fmaf(a[i], bf[j], acc[i][j]);
    }
    __syncthreads();
  }
#pragma unroll
  for (int i = 0; i < TM; i++){
    int row = row0 + ty * TM + i;
#pragma unroll
    for (int j = 0; j < TN; j++){
      int col = col0 + tx * TN + j;
      float v = acc[i][j];
      if (EPI >= 1) v += bias[col];
      if (EPI == 1) v *= scale;
      if (EPI == 3) v = fmaxf(v, 0.f);
      Cout[(size_t)row * N + col] = v;
    }
  }
}

// ---------------- P[b,h,d] = sum_t Wk[d, h*HD+t] * Q[b, h*HD+t] ----------------
#define PNB 8
__global__ __launch_bounds__(256) void k_pmat(const float* __restrict__ Q,
                                              const float* __restrict__ Wk,
                                              float* __restrict__ P){
  __shared__ float Qs[PNB][D];
  const int b0 = blockIdx.x * PNB;
  const int tid = threadIdx.x;
  for (int s = 0; s < PNB * D / 4 / 256; s++){
    int idx = tid + 256 * s;
    int r = idx >> 6, c = idx & 63;
    ((float4*)Qs[r])[c] = ((const float4*)(Q + (size_t)(b0 + r) * D))[c];
  }
  __syncthreads();
#pragma unroll
  for (int h = 0; h < NH; h++){
    const int d = tid;
    float acc[PNB];
#pragma unroll
    for (int bb = 0; bb < PNB; bb++) acc[bb] = 0.f;
    const float* wrow = Wk + (size_t)d * D + h * HD;
    float wreg[HD];
#pragma unroll
    for (int t4 = 0; t4 < HD / 4; t4++)
      *(float4*)&wreg[4 * t4] = *(const float4*)(wrow + 4 * t4);
#pragma unroll
    for (int t = 0; t < HD; t++){
      float w = wreg[t];
#pragma unroll
      for (int bb = 0; bb < PNB; bb++)
        acc[bb] = fmaf(Qs[bb][h * HD + t], w, acc[bb]);
    }
#pragma unroll
    for (int bb = 0; bb < PNB; bb++)
      P[(size_t)(b0 + bb) * (NH * D) + h * D + d] = acc[bb];
  }
}

// ---------------- attention core (MFMA scores, bf16 LDS tile) ----------------
// One block per query b. Waves stage E rows (f32->bf16) into swizzled LDS,
// one mfma_f32_16x16x32_bf16 chain per wave computes scores^T[h, l-tile],
// parallel 8x32 softmax, then per-lane VALU PV from the same LDS tile.
__global__ __launch_bounds__(256) void k_attn(const int* __restrict__ nei_idx,
                                              const void* __restrict__ nei_mask,
                                              const int* __restrict__ flagp,
                                              const float* __restrict__ emb,
                                              const float* __restrict__ P,
                                              float* __restrict__ C){
  const int b = blockIdx.x;
  const int tid = threadIdx.x;
  const int w = tid >> 6, lane = tid & 63;
  __shared__ __align__(16) unsigned short Ebf[64 * 256];  // 32 KB, swizzled
  __shared__ __align__(16) unsigned short Pl[9 * 256];    // 4.5 KB, row 8 = zeros
  __shared__ float sc[NH * LN_];                          // 2 KB  scores -> att
  __shared__ int   nid[LN_];
  __shared__ float mskv[LN_];
  char* eb = (char*)Ebf;
  char* pb = (char*)Pl;

  const int mf = flagp[0];
  if (tid < LN_){
    nid[tid] = nei_idx[(size_t)b * LN_ + tid];
    bool m;
    if (mf == 1)      m = ((const unsigned char*)nei_mask)[(size_t)b * LN_ + tid] != 0;
    else if (mf == 2) m = ((const float*)nei_mask)[(size_t)b * LN_ + tid] != 0.f;
    else              m = ((const int*)nei_mask)[(size_t)b * LN_ + tid] != 0;
    mskv[tid] = m ? 1.f : 0.f;
  }
  // stage P[b] (8 rows x 256 f32) -> bf16 LDS, swizzled; zero pad row 8
  {
    int r = tid >> 5, c8 = (tid & 31) * 8;               // 8 f32 per thread
    const float* src = P + (size_t)b * (NH * D) + (size_t)r * D + c8;
    float4 v0 = *(const float4*)(src);
    float4 v1 = *(const float4*)(src + 4);
    uint2 p0, p1;
    p0.x = (unsigned)f2bf(v0.x) | ((unsigned)f2bf(v0.y) << 16);
    p0.y = (unsigned)f2bf(v0.z) | ((unsigned)f2bf(v0.w) << 16);
    p1.x = (unsigned)f2bf(v1.x) | ((unsigned)f2bf(v1.y) << 16);
    p1.y = (unsigned)f2bf(v1.z) | ((unsigned)f2bf(v1.w) << 16);
    *(uint2*)(pb + ESWZ(r, r * 512 + c8 * 2)) = p0;
    *(uint2*)(pb + ESWZ(r, r * 512 + c8 * 2 + 8)) = p1;
    if (tid < 64) *(uint2*)(pb + 8 * 512 + tid * 8) = make_uint2(0u, 0u);  // row 8 zeros
  }
  __syncthreads();   // nid ready

  // stage 64 neighbor rows (f32 -> bf16, swizzled). wave w owns rows w*16..+15
#pragma unroll
  for (int i = 0; i < 16; i++){
    int l = w * 16 + i;
    float4 v = ((const float4*)(emb + (size_t)nid[l] * D))[lane];
    uint2 p;
    p.x = (unsigned)f2bf(v.x) | ((unsigned)f2bf(v.y) << 16);
    p.y = (unsigned)f2bf(v.z) | ((unsigned)f2bf(v.w) << 16);
    *(uint2*)(eb + ESWZ(l, l * 512 + lane * 8)) = p;
  }
  __syncthreads();

  // scores^T[h, l] via MFMA: A = P (rows h, zero-padded 8..15), B = E rows (cols l)
  {
    const int hr = lane & 15;
    const int arow = hr < 8 ? hr : 8;                    // zero row for pad
    const int bl = w * 16 + (lane & 15);
    const int koff = (lane >> 4) * 16;                   // byte offset of 8-elem chunk
    f32x4 acc = {0.f, 0.f, 0.f, 0.f};
#pragma unroll
    for (int kk = 0; kk < 8; kk++){
      short8 af = *(const short8*)(pb + ESWZ(arow, arow * 512 + kk * 64 + koff));
      short8 bf = *(const short8*)(eb + ESWZ(bl, bl * 512 + kk * 64 + koff));
      acc = __builtin_amdgcn_mfma_f32_16x16x32_bf16(af, bf, acc, 0, 0, 0);
    }
    // C/D layout: col = lane&15 (= l-tile idx), row h = (lane>>4)*4 + r
    int l = w * 16 + (lane & 15);
    int hb = (lane >> 4) * 4;
    if (hb < 8){
#pragma unroll
      for (int r = 0; r < 4; r++) sc[(hb + r) * LN_ + l] = acc[r];
    }
  }
  __syncthreads();

  // softmax: 8 h-groups x 32 threads, each thread covers l = j and j+32
  {
    int h = tid >> 5, j = tid & 31;
    float v0 = mskv[j]      > 0.5f ? -INFINITY : sc[h * LN_ + j];
    float v1 = mskv[j + 32] > 0.5f ? -INFINITY : sc[h * LN_ + j + 32];
    float m = fmaxf(v0, v1);
#pragma unroll
    for (int off = 16; off; off >>= 1) m = fmaxf(m, __shfl_xor(m, off, 64));
    float e0 = __expf(v0 - m), e1 = __expf(v1 - m);
    float s = e0 + e1;
#pragma unroll
    for (int off = 16; off; off >>= 1) s += __shfl_xor(s, off, 64);
    float inv = 1.f / s;
    sc[h * LN_ + j]      = e0 * inv;
    sc[h * LN_ + j + 32] = e1 * inv;
  }
  __syncthreads();

  // PV: wave w computes heads {2w, 2w+1}; lane owns d = lane*4..+3
  {
    const int h0 = w * 2, h1 = w * 2 + 1;
    float4 a0 = make_float4(0.f, 0.f, 0.f, 0.f);
    float4 a1 = make_float4(0.f, 0.f, 0.f, 0.f);
#pragma unroll 8
    for (int l = 0; l < 64; l++){
      uint2 raw = *(const uint2*)(eb + ESWZ(l, l * 512 + lane * 8));
      float e0 = __uint_as_float(raw.x << 16);
      float e1 = __uint_as_float(raw.x & 0xFFFF0000u);
      float e2 = __uint_as_float(raw.y << 16);
      float e3 = __uint_as_float(raw.y & 0xFFFF0000u);
      float t0 = sc[h0 * LN_ + l], t1 = sc[h1 * LN_ + l];
      a0.x = fmaf(t0, e0, a0.x); a0.y = fmaf(t0, e1, a0.y);
      a0.z = fmaf(t0, e2, a0.z); a0.w = fmaf(t0, e3, a0.w);
      a1.x = fmaf(t1, e0, a1.x); a1.y = fmaf(t1, e1, a1.y);
      a1.z = fmaf(t1, e2, a1.z); a1.w = fmaf(t1, e3, a1.w);
    }
    ((float4*)(C + (size_t)b * (NH * D) + h0 * D))[lane] = a0;
    ((float4*)(C + (size_t)b * (NH * D) + h1 * D))[lane] = a1;
  }
}

// ---------------- attout[b, h*HD+t] = sum_d C[b,h,d]*Wv[d,h*HD+t] + bv ----------------
__global__ __launch_bounds__(256) void k_attout(const float* __restrict__ C,
                                                const float* __restrict__ Wv,
                                                const float* __restrict__ bv,
                                                float* __restrict__ AO){
  const int h = blockIdx.y;
  const int b0 = blockIdx.x * 32;
  __shared__ float Cs[32][D + 4];
  __shared__ float Ws[D][HD];
  const int tid = threadIdx.x;
  for (int s = 0; s < 8; s++){
    int idx = tid + 256 * s;
    int r = idx >> 6, c = idx & 63;
    *(float4*)&Cs[r][4 * c] = ((const float4*)(C + (size_t)(b0 + r) * (NH * D) + h * D))[c];
  }
  for (int s = 0; s < 8; s++){
    int idx = tid + 256 * s;
    int d = idx >> 3, c = idx & 7;
    *(float4*)&Ws[d][4 * c] = *(const float4*)(Wv + (size_t)d * D + h * HD + 4 * c);
  }
  __syncthreads();
  const int rr = tid >> 3;
  const int tx = tid & 7;
  float4 acc = make_float4(0.f, 0.f, 0.f, 0.f);
#pragma unroll 4
  for (int d = 0; d < D; d++){
    float c = Cs[rr][d];
    float4 wv4 = *(float4*)&Ws[d][4 * tx];
    acc.x = fmaf(c, wv4.x, acc.x);
    acc.y = fmaf(c, wv4.y, acc.y);
    acc.z = fmaf(c, wv4.z, acc.z);
    acc.w = fmaf(c, wv4.w, acc.w);
  }
  float4 bb = *(const float4*)(bv + h * HD + 4 * tx);
  acc.x += bb.x; acc.y += bb.y; acc.z += bb.z; acc.w += bb.w;
  ((float4*)(AO + (size_t)(b0 + rr) * D + h * HD))[tx] = acc;
}

// ---------------- LayerNorm(out = LN(A+B)) ----------------
__global__ __launch_bounds__(256) void k_ln(const float* __restrict__ A,
                                            const float* __restrict__ Bv,
                                            const float* __restrict__ w,
                                            const float* __restrict__ bi,
                                            float* __restrict__ out){
  const int row = blockIdx.x, tid = threadIdx.x;
  const int wv = tid >> 6, lane = tid & 63;
  __shared__ float red[8];
  float v = A[(size_t)row * D + tid] + Bv[(size_t)row * D + tid];
  float s = wave_sum(v);
  if (lane == 0) red[wv] = s;
  __syncthreads();
  float mu = (red[0] + red[1] + red[2] + red[3]) * (1.f / D);
  float d = v - mu;
  float s2 = wave_sum(d * d);
  if (lane == 0) red[4 + wv] = s2;
  __syncthreads();
  float var = (red[4] + red[5] + red[6] + red[7]) * (1.f / D);
  out[(size_t)row * D + tid] = d * rsqrtf(var + EPSV) * w[tid] + bi[tid];
}

// ---------------- launch ----------------
extern "C" void kernel_launch(void* const* d_in, const int* in_sizes, int n_in,
                              void* d_out, int out_size, void* d_ws, size_t ws_size,
                              hipStream_t stream){
  (void)in_sizes; (void)n_in; (void)out_size; (void)ws_size;
  const int*   batch    = (const int*)d_in[0];
  const int*   nei_idx  = (const int*)d_in[1];
  const void*  nei_mask = d_in[2];
  const float* emb      = (const float*)d_in[3];
  const float* Wq = (const float*)d_in[4];  const float* bq = (const float*)d_in[5];
  const float* Wk = (const float*)d_in[6];  /* bk (d_in[7]) dropped: softmax-invariant */
  const float* Wv = (const float*)d_in[8];  const float* bv = (const float*)d_in[9];
  const float* Wo = (const float*)d_in[10]; const float* bo = (const float*)d_in[11];
  const float* W1 = (const float*)d_in[12]; const float* b1 = (const float*)d_in[13];
  const float* W2 = (const float*)d_in[14]; const float* b2 = (const float*)d_in[15];
  const float* ln1w = (const float*)d_in[16]; const float* ln1b = (const float*)d_in[17];
  const float* ln2w = (const float*)d_in[18]; const float* ln2b = (const float*)d_in[19];

  float* ws = (float*)d_ws;
  float* X  = ws;                       // [B,D]
  float* Qb = ws + (size_t)1 * 1048576; // [B,D]   (later reused as AO)
  float* P  = ws + (size_t)2 * 1048576; // [B,H,D] (later reused as C)
  float* Y  = ws + (size_t)10 * 1048576;// [B,D]
  float* S  = ws + (size_t)11 * 1048576;// [B,D]
  float* HH = ws + (size_t)12 * 1048576;// [B,DFF]
  float* F  = ws + (size_t)16 * 1048576;// [B,D]
  int*   flag = (int*)(ws + (size_t)17 * 1048576);
  float* out = (float*)d_out;

  const float qscale = 0.17677669529663687f;  // HD^-0.5

  k_detect<<<1, 256, 0, stream>>>((const unsigned int*)nei_mask, flag);
  k_gather<<<BQ * D / 4 / 256, 256, 0, stream>>>(batch, emb, X);
  // Q = (X@Wq + bq) * scale
  k_gemm<64, 32, 32, 4, 2, 1><<<dim3(D / 32, BQ / 64), 256, 0, stream>>>(X, Wq, bq, Qb, BQ, D, D, qscale);
  k_pmat<<<BQ / PNB, 256, 0, stream>>>(Qb, Wk, P);
  k_attn<<<BQ, 256, 0, stream>>>(nei_idx, nei_mask, flag, emb, P, P /* C aliases P */);
  k_attout<<<dim3(BQ / 32, NH), 256, 0, stream>>>(P, Wv, bv, Qb /* AO aliases Q */);
  // Y = AO@Wo + bo
  k_gemm<64, 32, 32, 4, 2, 2><<<dim3(D / 32, BQ / 64), 256, 0, stream>>>(Qb, Wo, bo, Y, BQ, D, D, 1.f);
  k_ln<<<BQ, 256, 0, stream>>>(X, Y, ln1w, ln1b, S);
  // HH = relu(S@W1 + b1)
  k_gemm<128, 64, 32, 8, 4, 3><<<dim3(DFF / 64, BQ / 128), 256, 0, stream>>>(S, W1, b1, HH, BQ, DFF, D, 1.f);
  // F = relu(HH@W2 + b2)
  k_gemm<64, 32, 32, 4, 2, 3><<<dim3(D / 32, BQ / 64), 256, 0, stream>>>(HH, W2, b2, F, BQ, D, DFF, 1.f);
  k_ln<<<BQ, 256, 0, stream>>>(S, F, ln2w, ln2b, out);
}

// Round 3
// 156.041 us; speedup vs baseline: 3.2652x; 1.8674x over previous
//
#include <hip/hip_runtime.h>
#include <hip/hip_bf16.h>
#include <math.h>

// Problem constants
#define BQ   4096
#define D    256
#define NH   8
#define HD   32
#define LN_  64     // neighbors per node
#define DFF  1024
#define EPSV 1e-5f

typedef __attribute__((ext_vector_type(8))) short short8;
typedef __attribute__((ext_vector_type(4))) float f32x4;

// LDS XOR swizzle (G4): spread 512B/128B-stride rows across banks; bijective involution.
#define ESWZ(row, byte) ((byte) ^ (((row) & 7) << 4))

// ---------------- helpers ----------------
__device__ __forceinline__ float wave_sum(float v){
#pragma unroll
  for (int off = 32; off; off >>= 1) v += __shfl_xor(v, off, 64);
  return v;
}
__device__ __forceinline__ unsigned short f2bf(float f){
  unsigned int u = __float_as_uint(f);
  unsigned int r = (u + 0x7FFFu + ((u >> 16) & 1u)) >> 16;   // RNE
  return (unsigned short)r;
}

// ---------------- weight transpose f32[K][N] -> bf16[N][K], + zero flags ----------------
__global__ __launch_bounds__(256) void k_wt(const float* __restrict__ Wq, const float* __restrict__ Wo,
                                            const float* __restrict__ W1, const float* __restrict__ W2,
                                            unsigned short* __restrict__ Wqt, unsigned short* __restrict__ Wot,
                                            unsigned short* __restrict__ W1t, unsigned short* __restrict__ W2t,
                                            int* __restrict__ flags){
  if (blockIdx.x == 0 && threadIdx.x == 0) flags[0] = 0;  // detect kernel runs after us (stream order)
  const float* src; unsigned short* dst; int K, N, t0;
  int bid = blockIdx.x;
  if (bid < 16)      { src = Wq; dst = Wqt; K = 256;  N = 256;  t0 = bid; }
  else if (bid < 32) { src = Wo; dst = Wot; K = 256;  N = 256;  t0 = bid - 16; }
  else if (bid < 96) { src = W1; dst = W1t; K = 256;  N = 1024; t0 = bid - 32; }
  else               { src = W2; dst = W2t; K = 1024; N = 256;  t0 = bid - 96; }
  const int ntx = N / 64;
  const int k0 = (t0 / ntx) * 64, n0 = (t0 % ntx) * 64;
  __shared__ float Ts[64][65];
  const int tid = threadIdx.x;
  {
    int r = tid >> 2, c4 = (tid & 3) * 16;
#pragma unroll
    for (int i = 0; i < 4; i++)
      *(float4*)&Ts[r][c4 + i * 4] = *(const float4*)(src + (size_t)(k0 + r) * N + n0 + c4 + i * 4);
  }
  __syncthreads();
  {
    int n = tid >> 2, kc = (tid & 3) * 16;
    unsigned int pk[8];
#pragma unroll
    for (int i = 0; i < 8; i++){
      unsigned int lo = f2bf(Ts[kc + 2 * i][n]);
      unsigned int hi = f2bf(Ts[kc + 2 * i + 1][n]);
      pk[i] = lo | (hi << 16);
    }
    unsigned short* orow = dst + (size_t)(n0 + n) * K + k0 + kc;
    *(uint4*)(orow)     = *(uint4*)&pk[0];
    *(uint4*)(orow + 8) = *(uint4*)&pk[4];
  }
}

// ---------------- parallel mask dtype detection ----------------
// bits: 2 = float32 pattern seen, 1 = packed-byte pattern seen
__global__ __launch_bounds__(256) void k_detectp(const unsigned int* __restrict__ m,
                                                 int* __restrict__ flags){
  int gid = blockIdx.x * 256 + threadIdx.x;   // words 0..65535 (256 KB)
  unsigned int v = m[gid];
  int bits = 0;
  if (v == 0x3F800000u) bits = 2;
  else if (v & 0xFFFFFF00u) bits = 1;
  int b2 = __any(bits & 2) ? 2 : 0;
  int b1 = __any(bits & 1) ? 1 : 0;
  if ((threadIdx.x & 63) == 0 && (b1 | b2)) atomicOr(flags, b1 | b2);
}

// ---------------- gather query-node embeddings (f32 + bf16 copies) ----------------
__global__ __launch_bounds__(256) void k_gather(const int* __restrict__ batch,
                                                const float* __restrict__ emb,
                                                float* __restrict__ X,
                                                unsigned short* __restrict__ Xb){
  int gid = blockIdx.x * 256 + threadIdx.x;   // over BQ*D/4 float4
  int b = gid >> 6;
  int c = gid & 63;
  float4 v = ((const float4*)(emb + (size_t)batch[b] * D))[c];
  ((float4*)(X + (size_t)b * D))[c] = v;
  uint2 p;
  p.x = (unsigned)f2bf(v.x) | ((unsigned)f2bf(v.y) << 16);
  p.y = (unsigned)f2bf(v.z) | ((unsigned)f2bf(v.w) << 16);
  ((uint2*)Xb)[gid] = p;
}

// ---------------- bf16 MFMA GEMM ----------------
// C[M,N] = epi(A[M,K] @ Bt[N,K]^T); A,Bt bf16 row-major. 4 waves as 2x2.
// EPI: 1 (acc+bias)*scale, 2 acc+bias, 3 relu(acc+bias). OUTBF: bf16 output.
template<int BM, int BN, int EPI, bool OUTBF>
__global__ __launch_bounds__(256) void k_mgemm(const unsigned short* __restrict__ A,
                                               const unsigned short* __restrict__ Bt,
                                               const float* __restrict__ bias,
                                               void* __restrict__ Cout,
                                               int M, int N, int K, float scale){
  constexpr int BK = 64;
  constexpr int WM = BM / 2, WN = BN / 2;
  constexpr int MR = WM / 16, NR = WN / 16;
  __shared__ __align__(16) unsigned short As[BM * BK];
  __shared__ __align__(16) unsigned short Bs[BN * BK];
  char* ab = (char*)As; char* bb = (char*)Bs;
  const int tid = threadIdx.x;
  const int w = tid >> 6, lane = tid & 63;
  const int wm = w >> 1, wn = w & 1;
  const int row0 = blockIdx.y * BM, col0 = blockIdx.x * BN;
  f32x4 acc[MR][NR];
#pragma unroll
  for (int m = 0; m < MR; m++)
#pragma unroll
    for (int n = 0; n < NR; n++) acc[m][n] = (f32x4){0.f, 0.f, 0.f, 0.f};

  constexpr int AIT = BM * 8 / 256;   // 16B chunks / 256 threads
  constexpr int BIT = BN * 8 / 256;

  for (int k0 = 0; k0 < K; k0 += BK){
#pragma unroll
    for (int s = 0; s < AIT; s++){
      int c = s * 256 + tid;
      int r = c >> 3, jj = c & 7;
      uint4 v = *(const uint4*)(A + (size_t)(row0 + r) * K + k0 + jj * 8);
      *(uint4*)(ab + ESWZ(r, r * 128 + jj * 16)) = v;
    }
#pragma unroll
    for (int s = 0; s < BIT; s++){
      int c = s * 256 + tid;
      int r = c >> 3, jj = c & 7;
      uint4 v = *(const uint4*)(Bt + (size_t)(col0 + r) * K + k0 + jj * 8);
      *(uint4*)(bb + ESWZ(r, r * 128 + jj * 16)) = v;
    }
    __syncthreads();
#pragma unroll
    for (int kk = 0; kk < 2; kk++){
      short8 af[MR], bf[NR];
#pragma unroll
      for (int m = 0; m < MR; m++){
        int r = wm * WM + m * 16 + (lane & 15);
        af[m] = *(const short8*)(ab + ESWZ(r, r * 128 + (kk * 4 + (lane >> 4)) * 16));
      }
#pragma unroll
      for (int n = 0; n < NR; n++){
        int r = wn * WN + n * 16 + (lane & 15);
        bf[n] = *(const short8*)(bb + ESWZ(r, r * 128 + (kk * 4 + (lane >> 4)) * 16));
      }
#pragma unroll
      for (int m = 0; m < MR; m++)
#pragma unroll
        for (int n = 0; n < NR; n++)
          acc[m][n] = __builtin_amdgcn_mfma_f32_16x16x32_bf16(af[m], bf[n], acc[m][n], 0, 0, 0);
    }
    __syncthreads();
  }
  // epilogue: D row = A-row = (lane>>4)*4+r, D col = B-row = lane&15 (HW-verified r2)
#pragma unroll
  for (int m = 0; m < MR; m++){
#pragma unroll
    for (int n = 0; n < NR; n++){
      int col = col0 + wn * WN + n * 16 + (lane & 15);
      float bsv = bias[col];
      int rbase = row0 + wm * WM + m * 16 + (lane >> 4) * 4;
#pragma unroll
      for (int r = 0; r < 4; r++){
        float v = acc[m][n][r] + bsv;
        if (EPI == 1) v *= scale;
        if (EPI == 3) v = fmaxf(v, 0.f);
        if (OUTBF) ((unsigned short*)Cout)[(size_t)(rbase + r) * N + col] = f2bf(v);
        else       ((float*)Cout)[(size_t)(rbase + r) * N + col] = v;
      }
    }
  }
}

// ---------------- P[b,h,d] = sum_t Wk[d, h*HD+t] * Q[b, h*HD+t] ----------------
#define PNB 8
__global__ __launch_bounds__(256) void k_pmat(const float* __restrict__ Q,
                                              const float* __restrict__ Wk,
                                              float* __restrict__ P){
  __shared__ float Qs[PNB][D];
  const int b0 = blockIdx.x * PNB;
  const int tid = threadIdx.x;
  for (int s = 0; s < PNB * D / 4 / 256; s++){
    int idx = tid + 256 * s;
    int r = idx >> 6, c = idx & 63;
    ((float4*)Qs[r])[c] = ((const float4*)(Q + (size_t)(b0 + r) * D))[c];
  }
  __syncthreads();
#pragma unroll
  for (int h = 0; h < NH; h++){
    const int d = tid;
    float acc[PNB];
#pragma unroll
    for (int bb = 0; bb < PNB; bb++) acc[bb] = 0.f;
    const float* wrow = Wk + (size_t)d * D + h * HD;
    float wreg[HD];
#pragma unroll
    for (int t4 = 0; t4 < HD / 4; t4++)
      *(float4*)&wreg[4 * t4] = *(const float4*)(wrow + 4 * t4);
#pragma unroll
    for (int t = 0; t < HD; t++){
      float w = wreg[t];
#pragma unroll
      for (int bb = 0; bb < PNB; bb++)
        acc[bb] = fmaf(Qs[bb][h * HD + t], w, acc[bb]);
    }
#pragma unroll
    for (int bb = 0; bb < PNB; bb++)
      P[(size_t)(b0 + bb) * (NH * D) + h * D + d] = acc[bb];
  }
}

// ---------------- attention core (MFMA scores, bf16 LDS tile) ----------------
__global__ __launch_bounds__(256) void k_attn(const int* __restrict__ nei_idx,
                                              const void* __restrict__ nei_mask,
                                              const int* __restrict__ flagp,
                                              const float* __restrict__ emb,
                                              const float* __restrict__ P,
                                              float* __restrict__ C){
  const int b = blockIdx.x;
  const int tid = threadIdx.x;
  const int w = tid >> 6, lane = tid & 63;
  __shared__ __align__(16) unsigned short Ebf[64 * 256];  // 32 KB, swizzled
  __shared__ __align__(16) unsigned short Pl[9 * 256];    // 4.5 KB, row 8 = zeros
  __shared__ float sc[NH * LN_];
  __shared__ int   nid[LN_];
  __shared__ float mskv[LN_];
  char* eb = (char*)Ebf;
  char* pb = (char*)Pl;

  const int fl = flagp[0];
  const int mf = (fl & 2) ? 2 : ((fl & 1) ? 1 : 0);
  if (tid < LN_){
    nid[tid] = nei_idx[(size_t)b * LN_ + tid];
    bool m;
    if (mf == 1)      m = ((const unsigned char*)nei_mask)[(size_t)b * LN_ + tid] != 0;
    else if (mf == 2) m = ((const float*)nei_mask)[(size_t)b * LN_ + tid] != 0.f;
    else              m = ((const int*)nei_mask)[(size_t)b * LN_ + tid] != 0;
    mskv[tid] = m ? 1.f : 0.f;
  }
  {
    int r = tid >> 5, c8 = (tid & 31) * 8;
    const float* src = P + (size_t)b * (NH * D) + (size_t)r * D + c8;
    float4 v0 = *(const float4*)(src);
    float4 v1 = *(const float4*)(src + 4);
    uint2 p0, p1;
    p0.x = (unsigned)f2bf(v0.x) | ((unsigned)f2bf(v0.y) << 16);
    p0.y = (unsigned)f2bf(v0.z) | ((unsigned)f2bf(v0.w) << 16);
    p1.x = (unsigned)f2bf(v1.x) | ((unsigned)f2bf(v1.y) << 16);
    p1.y = (unsigned)f2bf(v1.z) | ((unsigned)f2bf(v1.w) << 16);
    *(uint2*)(pb + ESWZ(r, r * 512 + c8 * 2)) = p0;
    *(uint2*)(pb + ESWZ(r, r * 512 + c8 * 2 + 8)) = p1;
    if (tid < 64) *(uint2*)(pb + 8 * 512 + tid * 8) = make_uint2(0u, 0u);
  }
  __syncthreads();

#pragma unroll
  for (int i = 0; i < 16; i++){
    int l = w * 16 + i;
    float4 v = ((const float4*)(emb + (size_t)nid[l] * D))[lane];
    uint2 p;
    p.x = (unsigned)f2bf(v.x) | ((unsigned)f2bf(v.y) << 16);
    p.y = (unsigned)f2bf(v.z) | ((unsigned)f2bf(v.w) << 16);
    *(uint2*)(eb + ESWZ(l, l * 512 + lane * 8)) = p;
  }
  __syncthreads();

  {
    const int hr = lane & 15;
    const int arow = hr < 8 ? hr : 8;
    const int bl = w * 16 + (lane & 15);
    const int koff = (lane >> 4) * 16;
    f32x4 acc = {0.f, 0.f, 0.f, 0.f};
#pragma unroll
    for (int kk = 0; kk < 8; kk++){
      short8 af = *(const short8*)(pb + ESWZ(arow, arow * 512 + kk * 64 + koff));
      short8 bf = *(const short8*)(eb + ESWZ(bl, bl * 512 + kk * 64 + koff));
      acc = __builtin_amdgcn_mfma_f32_16x16x32_bf16(af, bf, acc, 0, 0, 0);
    }
    int l = w * 16 + (lane & 15);
    int hb = (lane >> 4) * 4;
    if (hb < 8){
#pragma unroll
      for (int r = 0; r < 4; r++) sc[(hb + r) * LN_ + l] = acc[r];
    }
  }
  __syncthreads();

  {
    int h = tid >> 5, j = tid & 31;
    float v0 = mskv[j]      > 0.5f ? -INFINITY : sc[h * LN_ + j];
    float v1 = mskv[j + 32] > 0.5f ? -INFINITY : sc[h * LN_ + j + 32];
    float m = fmaxf(v0, v1);
#pragma unroll
    for (int off = 16; off; off >>= 1) m = fmaxf(m, __shfl_xor(m, off, 64));
    float e0 = __expf(v0 - m), e1 = __expf(v1 - m);
    float s = e0 + e1;
#pragma unroll
    for (int off = 16; off; off >>= 1) s += __shfl_xor(s, off, 64);
    float inv = 1.f / s;
    sc[h * LN_ + j]      = e0 * inv;
    sc[h * LN_ + j + 32] = e1 * inv;
  }
  __syncthreads();

  {
    const int h0 = w * 2, h1 = w * 2 + 1;
    float4 a0 = make_float4(0.f, 0.f, 0.f, 0.f);
    float4 a1 = make_float4(0.f, 0.f, 0.f, 0.f);
#pragma unroll 8
    for (int l = 0; l < 64; l++){
      uint2 raw = *(const uint2*)(eb + ESWZ(l, l * 512 + lane * 8));
      float e0 = __uint_as_float(raw.x << 16);
      float e1 = __uint_as_float(raw.x & 0xFFFF0000u);
      float e2 = __uint_as_float(raw.y << 16);
      float e3 = __uint_as_float(raw.y & 0xFFFF0000u);
      float t0 = sc[h0 * LN_ + l], t1 = sc[h1 * LN_ + l];
      a0.x = fmaf(t0, e0, a0.x); a0.y = fmaf(t0, e1, a0.y);
      a0.z = fmaf(t0, e2, a0.z); a0.w = fmaf(t0, e3, a0.w);
      a1.x = fmaf(t1, e0, a1.x); a1.y = fmaf(t1, e1, a1.y);
      a1.z = fmaf(t1, e2, a1.z); a1.w = fmaf(t1, e3, a1.w);
    }
    ((float4*)(C + (size_t)b * (NH * D) + h0 * D))[lane] = a0;
    ((float4*)(C + (size_t)b * (NH * D) + h1 * D))[lane] = a1;
  }
}

// ---------------- attout -> bf16: AO[b, h*HD+t] = sum_d C[b,h,d]*Wv[d,h*HD+t] + bv ----------------
__global__ __launch_bounds__(256) void k_attout(const float* __restrict__ C,
                                                const float* __restrict__ Wv,
                                                const float* __restrict__ bv,
                                                unsigned short* __restrict__ AOb){
  const int h = blockIdx.y;
  const int b0 = blockIdx.x * 32;
  __shared__ float Cs[32][D + 4];
  __shared__ float Ws[D][HD];
  const int tid = threadIdx.x;
  for (int s = 0; s < 8; s++){
    int idx = tid + 256 * s;
    int r = idx >> 6, c = idx & 63;
    *(float4*)&Cs[r][4 * c] = ((const float4*)(C + (size_t)(b0 + r) * (NH * D) + h * D))[c];
  }
  for (int s = 0; s < 8; s++){
    int idx = tid + 256 * s;
    int d = idx >> 3, c = idx & 7;
    *(float4*)&Ws[d][4 * c] = *(const float4*)(Wv + (size_t)d * D + h * HD + 4 * c);
  }
  __syncthreads();
  const int rr = tid >> 3;
  const int tx = tid & 7;
  float4 acc = make_float4(0.f, 0.f, 0.f, 0.f);
#pragma unroll 4
  for (int d = 0; d < D; d++){
    float c = Cs[rr][d];
    float4 wv4 = *(float4*)&Ws[d][4 * tx];
    acc.x = fmaf(c, wv4.x, acc.x);
    acc.y = fmaf(c, wv4.y, acc.y);
    acc.z = fmaf(c, wv4.z, acc.z);
    acc.w = fmaf(c, wv4.w, acc.w);
  }
  float4 bb = *(const float4*)(bv + h * HD + 4 * tx);
  acc.x += bb.x; acc.y += bb.y; acc.z += bb.z; acc.w += bb.w;
  uint2 p;
  p.x = (unsigned)f2bf(acc.x) | ((unsigned)f2bf(acc.y) << 16);
  p.y = (unsigned)f2bf(acc.z) | ((unsigned)f2bf(acc.w) << 16);
  *(uint2*)(AOb + (size_t)(b0 + rr) * D + h * HD + tx * 4) = p;
}

// ---------------- LayerNorm(out = LN(A+B)), optional bf16 copy ----------------
__global__ __launch_bounds__(256) void k_ln(const float* __restrict__ A,
                                            const float* __restrict__ Bv,
                                            const float* __restrict__ w,
                                            const float* __restrict__ bi,
                                            float* __restrict__ out,
                                            unsigned short* __restrict__ outb){
  const int row = blockIdx.x, tid = threadIdx.x;
  const int wv = tid >> 6, lane = tid & 63;
  __shared__ float red[8];
  float v = A[(size_t)row * D + tid] + Bv[(size_t)row * D + tid];
  float s = wave_sum(v);
  if (lane == 0) red[wv] = s;
  __syncthreads();
  float mu = (red[0] + red[1] + red[2] + red[3]) * (1.f / D);
  float d = v - mu;
  float s2 = wave_sum(d * d);
  if (lane == 0) red[4 + wv] = s2;
  __syncthreads();
  float var = (red[4] + red[5] + red[6] + red[7]) * (1.f / D);
  float res = d * rsqrtf(var + EPSV) * w[tid] + bi[tid];
  out[(size_t)row * D + tid] = res;
  if (outb) outb[(size_t)row * D + tid] = f2bf(res);
}

// ---------------- launch ----------------
extern "C" void kernel_launch(void* const* d_in, const int* in_sizes, int n_in,
                              void* d_out, int out_size, void* d_ws, size_t ws_size,
                              hipStream_t stream){
  (void)in_sizes; (void)n_in; (void)out_size; (void)ws_size;
  const int*   batch    = (const int*)d_in[0];
  const int*   nei_idx  = (const int*)d_in[1];
  const void*  nei_mask = d_in[2];
  const float* emb      = (const float*)d_in[3];
  const float* Wq = (const float*)d_in[4];  const float* bq = (const float*)d_in[5];
  const float* Wk = (const float*)d_in[6];  /* bk dropped: softmax-invariant */
  const float* Wv = (const float*)d_in[8];  const float* bv = (const float*)d_in[9];
  const float* Wo = (const float*)d_in[10]; const float* bo = (const float*)d_in[11];
  const float* W1 = (const float*)d_in[12]; const float* b1 = (const float*)d_in[13];
  const float* W2 = (const float*)d_in[14]; const float* b2 = (const float*)d_in[15];
  const float* ln1w = (const float*)d_in[16]; const float* ln1b = (const float*)d_in[17];
  const float* ln2w = (const float*)d_in[18]; const float* ln2b = (const float*)d_in[19];

  float* ws = (float*)d_ws;
  // slot = 4 MiB (1048576 floats)
  float* X  = ws;                        // slot 0
  float* Qb = ws + (size_t)1 * 1048576;  // slot 1 (F aliases after pmat)
  float* P  = ws + (size_t)2 * 1048576;  // slots 2-9: P, then C; later Sb/HHb sub-use
  float* Y  = ws + (size_t)10 * 1048576; // slot 10
  float* S  = ws + (size_t)11 * 1048576; // slot 11
  float* F  = Qb;                        // reuse slot 1 (Qb dead after k_pmat)
  unsigned short* Sb  = (unsigned short*)(ws + (size_t)2 * 1048576);  // slot 2 (C dead after attout)
  unsigned short* HHb = (unsigned short*)(ws + (size_t)3 * 1048576);  // slots 3-4
  unsigned short* Xb  = (unsigned short*)(ws + (size_t)5 * 1048576);  // slot 5 (dead before pmat writes P)
  char* s12 = (char*)(ws + (size_t)12 * 1048576);                     // slot 12
  unsigned short* AOb = (unsigned short*)s12;                          // 2 MiB
  unsigned short* Wqt = (unsigned short*)(s12 + (2u << 20));           // 128 KiB
  unsigned short* Wot = (unsigned short*)(s12 + (2u << 20) + (128u << 10));
  unsigned short* W1t = (unsigned short*)(s12 + (2u << 20) + (256u << 10)); // 512 KiB
  unsigned short* W2t = (unsigned short*)(s12 + (2u << 20) + (768u << 10)); // 512 KiB
  int* flags = (int*)(s12 + (3u << 20) + (256u << 10));
  float* out = (float*)d_out;

  const float qscale = 0.17677669529663687f;  // HD^-0.5

  k_wt<<<160, 256, 0, stream>>>(Wq, Wo, W1, W2, Wqt, Wot, W1t, W2t, flags);
  k_detectp<<<256, 256, 0, stream>>>((const unsigned int*)nei_mask, flags);
  k_gather<<<BQ * D / 4 / 256, 256, 0, stream>>>(batch, emb, X, Xb);
  // Q = (X@Wq + bq) * scale  [f32 out]
  k_mgemm<64, 64, 1, false><<<dim3(D / 64, BQ / 64), 256, 0, stream>>>(Xb, Wqt, bq, Qb, BQ, D, D, qscale);
  k_pmat<<<BQ / PNB, 256, 0, stream>>>(Qb, Wk, P);
  k_attn<<<BQ, 256, 0, stream>>>(nei_idx, nei_mask, flags, emb, P, P /* C aliases P */);
  k_attout<<<dim3(BQ / 32, NH), 256, 0, stream>>>(P, Wv, bv, AOb);
  // Y = AO@Wo + bo  [f32 out]
  k_mgemm<64, 64, 2, false><<<dim3(D / 64, BQ / 64), 256, 0, stream>>>(AOb, Wot, bo, Y, BQ, D, D, 1.f);
  k_ln<<<BQ, 256, 0, stream>>>(X, Y, ln1w, ln1b, S, Sb);
  // HH = relu(S@W1 + b1)  [bf16 out]
  k_mgemm<128, 64, 3, true><<<dim3(DFF / 64, BQ / 128), 256, 0, stream>>>(Sb, W1t, b1, HHb, BQ, DFF, D, 1.f);
  // F = relu(HH@W2 + b2)  [f32 out]
  k_mgemm<64, 64, 3, false><<<dim3(D / 64, BQ / 64), 256, 0, stream>>>(HHb, W2t, b2, F, BQ, D, DFF, 1.f);
  k_ln<<<BQ, 256, 0, stream>>>(S, F, ln2w, ln2b, out, nullptr);
}

// Round 4
// 132.403 us; speedup vs baseline: 3.8481x; 1.1785x over previous
//
#include <hip/hip_runtime.h>
#include <hip/hip_bf16.h>
#include <math.h>

// Problem constants
#define BQ   4096
#define D    256
#define NH   8
#define HD   32
#define LN_  64     // neighbors per node
#define DFF  1024
#define EPSV 1e-5f
#define QSCALE 0.17677669529663687f  // HD^-0.5

typedef __attribute__((ext_vector_type(8))) short short8;
typedef __attribute__((ext_vector_type(4))) float f32x4;

// LDS XOR swizzle (G4): spread 512B/128B-stride rows across banks; bijective involution.
#define ESWZ(row, byte) ((byte) ^ (((row) & 7) << 4))

// ---------------- helpers ----------------
__device__ __forceinline__ float wave_sum(float v){
#pragma unroll
  for (int off = 32; off; off >>= 1) v += __shfl_xor(v, off, 64);
  return v;
}
__device__ __forceinline__ unsigned short f2bf(float f){
  unsigned int u = __float_as_uint(f);
  unsigned int r = (u + 0x7FFFu + ((u >> 16) & 1u)) >> 16;   // RNE
  return (unsigned short)r;
}

// ---------------- mega-prep kernel (block-range dispatch) ----------------
// blocks 0-63    : W1 [256][1024] -> W1t bf16 [1024][256]
// blocks 64-127  : W2 [1024][256] -> W2t bf16 [256][1024]
// blocks 128-255 : Mt bf16 [2048][256], Mt[(h,d)][c] = QSCALE*sum_t Wq[c,ht]*Wk[d,ht]; + pb
// blocks 256-383 : Gt bf16 [256][2048], Gt[n][(h,d)] = sum_t Wv[d,ht]*Wo[ht,n]
// block  384     : bo2[n] = bo[n] + sum_j bv[j]*Wo[j,n]
// blocks 385-640 : mask dtype detect (atomicOr into flags; flags pre-zeroed by memset)
// blocks 641-1664: gather X (f32) + Xb (bf16)
__global__ __launch_bounds__(256) void k_prep(
    const float* __restrict__ Wq, const float* __restrict__ Wk,
    const float* __restrict__ Wv, const float* __restrict__ Wo,
    const float* __restrict__ W1, const float* __restrict__ W2,
    const float* __restrict__ bq, const float* __restrict__ bv,
    const float* __restrict__ bo,
    const int* __restrict__ batch, const float* __restrict__ emb,
    const unsigned int* __restrict__ maskw,
    unsigned short* __restrict__ W1t, unsigned short* __restrict__ W2t,
    unsigned short* __restrict__ Mt, unsigned short* __restrict__ Gt,
    float* __restrict__ pb, float* __restrict__ bo2,
    float* __restrict__ X, unsigned short* __restrict__ Xb,
    int* __restrict__ flags){
  __shared__ float smem[4224];
  const int bid = blockIdx.x;
  const int tid = threadIdx.x;

  if (bid < 128){
    // ---- weight transpose f32[K][N] -> bf16[N][K] ----
    const float* src; unsigned short* dst; int K, N, t0;
    if (bid < 64){ src = W1; dst = W1t; K = 256;  N = 1024; t0 = bid; }
    else         { src = W2; dst = W2t; K = 1024; N = 256;  t0 = bid - 64; }
    const int ntx = N / 64;
    const int k0 = (t0 / ntx) * 64, n0 = (t0 % ntx) * 64;
    float (*Ts)[65] = (float(*)[65])smem;
    {
      int r = tid >> 2, c4 = (tid & 3) * 16;
#pragma unroll
      for (int i = 0; i < 4; i++)
        *(float4*)&Ts[r][c4 + i * 4] = *(const float4*)(src + (size_t)(k0 + r) * N + n0 + c4 + i * 4);
    }
    __syncthreads();
    {
      int n = tid >> 2, kc = (tid & 3) * 16;
      unsigned int pk[8];
#pragma unroll
      for (int i = 0; i < 8; i++){
        unsigned int lo = f2bf(Ts[kc + 2 * i][n]);
        unsigned int hi = f2bf(Ts[kc + 2 * i + 1][n]);
        pk[i] = lo | (hi << 16);
      }
      unsigned short* orow = dst + (size_t)(n0 + n) * K + k0 + kc;
      *(uint4*)(orow)     = *(uint4*)&pk[0];
      *(uint4*)(orow + 8) = *(uint4*)&pk[4];
    }
    return;
  }
  if (bid < 256){
    // ---- Mt tile: hd0 = 64-chunk of (h,d), c0 = 64-chunk of c ----
    int t0 = bid - 128;
    int hd0 = (t0 & 31) * 64, c0 = (t0 >> 5) * 64;
    int h = hd0 >> 8, d0 = hd0 & 255;
    float (*WqS)[33] = (float(*)[33])smem;          // [c 64][t 32]
    float (*WkS)[33] = (float(*)[33])(smem + 64 * 33); // [d 64][t 32]
#pragma unroll
    for (int s = 0; s < 2; s++){
      int idx = tid + s * 256;
      int row = idx >> 3, c4 = (idx & 7) * 4;
      *(float4*)&WqS[row][c4] = *(const float4*)(Wq + (size_t)(c0 + row) * 256 + h * 32 + c4);
      *(float4*)&WkS[row][c4] = *(const float4*)(Wk + (size_t)(d0 + row) * 256 + h * 32 + c4);
    }
    __syncthreads();
    int jo = (tid >> 4) * 4, io = (tid & 15) * 4;   // jo: hd rows, io: c cols
    float acc[4][4];
#pragma unroll
    for (int j = 0; j < 4; j++)
#pragma unroll
      for (int i = 0; i < 4; i++) acc[j][i] = 0.f;
#pragma unroll
    for (int t = 0; t < 32; t++){
#pragma unroll
      for (int j = 0; j < 4; j++){
        float kv = WkS[jo + j][t];
#pragma unroll
        for (int i = 0; i < 4; i++) acc[j][i] = fmaf(kv, WqS[io + i][t], acc[j][i]);
      }
    }
#pragma unroll
    for (int j = 0; j < 4; j++){
      uint2 o;
      o.x = (unsigned)f2bf(acc[j][0] * QSCALE) | ((unsigned)f2bf(acc[j][1] * QSCALE) << 16);
      o.y = (unsigned)f2bf(acc[j][2] * QSCALE) | ((unsigned)f2bf(acc[j][3] * QSCALE) << 16);
      *(uint2*)(Mt + (size_t)(hd0 + jo + j) * 256 + c0 + io) = o;
    }
    if (c0 == 0 && tid < 64){
      float s = 0.f;
#pragma unroll
      for (int t = 0; t < 32; t++) s = fmaf(WkS[tid][t], bq[h * 32 + t], s);
      pb[hd0 + tid] = s * QSCALE;
    }
    return;
  }
  if (bid < 384){
    // ---- Gt tile: n0 = 64-chunk of n, hd0 = 64-chunk of (h,d) ----
    int t0 = bid - 256;
    int hd0 = (t0 & 31) * 64, n0 = (t0 >> 5) * 64;
    int h = hd0 >> 8, d0 = hd0 & 255;
    float (*WvS)[33] = (float(*)[33])smem;             // [d 64][t 32]
    float (*WoS)[65] = (float(*)[65])(smem + 64 * 33); // [t 32][n 64]
#pragma unroll
    for (int s = 0; s < 2; s++){
      int idx = tid + s * 256;
      int row = idx >> 3, c4 = (idx & 7) * 4;
      *(float4*)&WvS[row][c4] = *(const float4*)(Wv + (size_t)(d0 + row) * 256 + h * 32 + c4);
      int row2 = idx >> 4, c42 = (idx & 15) * 4;
      *(float4*)&WoS[row2][c42] = *(const float4*)(Wo + (size_t)(h * 32 + row2) * 256 + n0 + c42);
    }
    __syncthreads();
    int jo = (tid >> 4) * 4, io = (tid & 15) * 4;   // jo: hd, io: n
    float acc[4][4];                                 // [i=n][j=hd]
#pragma unroll
    for (int i = 0; i < 4; i++)
#pragma unroll
      for (int j = 0; j < 4; j++) acc[i][j] = 0.f;
#pragma unroll
    for (int t = 0; t < 32; t++){
#pragma unroll
      for (int i = 0; i < 4; i++){
        float ov = WoS[t][io + i];
#pragma unroll
        for (int j = 0; j < 4; j++) acc[i][j] = fmaf(ov, WvS[jo + j][t], acc[i][j]);
      }
    }
#pragma unroll
    for (int i = 0; i < 4; i++){
      uint2 o;
      o.x = (unsigned)f2bf(acc[i][0]) | ((unsigned)f2bf(acc[i][1]) << 16);
      o.y = (unsigned)f2bf(acc[i][2]) | ((unsigned)f2bf(acc[i][3]) << 16);
      *(uint2*)(Gt + (size_t)(n0 + io + i) * 2048 + hd0 + jo) = o;
    }
    return;
  }
  if (bid == 384){
    int n = tid;
    float s = bo[n];
    for (int j = 0; j < 256; j++) s = fmaf(bv[j], Wo[(size_t)j * 256 + n], s);
    bo2[n] = s;
    return;
  }
  if (bid < 641){
    // ---- mask dtype detect over first 65536 words ----
    int idx = (bid - 385) * 256 + tid;
    unsigned int v = maskw[idx];
    int bits = 0;
    if (v == 0x3F800000u) bits = 2;
    else if (v & 0xFFFFFF00u) bits = 1;
    int b2 = __any(bits & 2) ? 2 : 0;
    int b1 = __any(bits & 1) ? 1 : 0;
    if ((tid & 63) == 0 && (b1 | b2)) atomicOr(flags, b1 | b2);
    return;
  }
  {
    // ---- gather X + Xb ----
    int gid = (bid - 641) * 256 + tid;   // over BQ*D/4 float4
    int b = gid >> 6, c = gid & 63;
    float4 v = ((const float4*)(emb + (size_t)batch[b] * D))[c];
    ((float4*)(X + (size_t)b * D))[c] = v;
    uint2 p;
    p.x = (unsigned)f2bf(v.x) | ((unsigned)f2bf(v.y) << 16);
    p.y = (unsigned)f2bf(v.z) | ((unsigned)f2bf(v.w) << 16);
    ((uint2*)Xb)[gid] = p;
  }
}

// ---------------- bf16 MFMA GEMM ----------------
// C[M,N] = epi(A[M,K] @ Bt[N,K]^T); A,Bt bf16 row-major. 4 waves as 2x2.
// EPI: 2 acc+bias, 3 relu(acc+bias). OUTBF: bf16 output.
template<int BM, int BN, int EPI, bool OUTBF>
__global__ __launch_bounds__(256) void k_mgemm(const unsigned short* __restrict__ A,
                                               const unsigned short* __restrict__ Bt,
                                               const float* __restrict__ bias,
                                               void* __restrict__ Cout,
                                               int M, int N, int K){
  constexpr int BK = 64;
  constexpr int WM = BM / 2, WN = BN / 2;
  constexpr int MR = WM / 16, NR = WN / 16;
  __shared__ __align__(16) unsigned short As[BM * BK];
  __shared__ __align__(16) unsigned short Bs[BN * BK];
  char* ab = (char*)As; char* bb = (char*)Bs;
  const int tid = threadIdx.x;
  const int w = tid >> 6, lane = tid & 63;
  const int wm = w >> 1, wn = w & 1;
  const int row0 = blockIdx.y * BM, col0 = blockIdx.x * BN;
  f32x4 acc[MR][NR];
#pragma unroll
  for (int m = 0; m < MR; m++)
#pragma unroll
    for (int n = 0; n < NR; n++) acc[m][n] = (f32x4){0.f, 0.f, 0.f, 0.f};

  constexpr int AIT = BM * 8 / 256;   // 16B chunks / 256 threads
  constexpr int BIT = BN * 8 / 256;

  for (int k0 = 0; k0 < K; k0 += BK){
#pragma unroll
    for (int s = 0; s < AIT; s++){
      int c = s * 256 + tid;
      int r = c >> 3, jj = c & 7;
      uint4 v = *(const uint4*)(A + (size_t)(row0 + r) * K + k0 + jj * 8);
      *(uint4*)(ab + ESWZ(r, r * 128 + jj * 16)) = v;
    }
#pragma unroll
    for (int s = 0; s < BIT; s++){
      int c = s * 256 + tid;
      int r = c >> 3, jj = c & 7;
      uint4 v = *(const uint4*)(Bt + (size_t)(col0 + r) * K + k0 + jj * 8);
      *(uint4*)(bb + ESWZ(r, r * 128 + jj * 16)) = v;
    }
    __syncthreads();
#pragma unroll
    for (int kk = 0; kk < 2; kk++){
      short8 af[MR], bf[NR];
#pragma unroll
      for (int m = 0; m < MR; m++){
        int r = wm * WM + m * 16 + (lane & 15);
        af[m] = *(const short8*)(ab + ESWZ(r, r * 128 + (kk * 4 + (lane >> 4)) * 16));
      }
#pragma unroll
      for (int n = 0; n < NR; n++){
        int r = wn * WN + n * 16 + (lane & 15);
        bf[n] = *(const short8*)(bb + ESWZ(r, r * 128 + (kk * 4 + (lane >> 4)) * 16));
      }
#pragma unroll
      for (int m = 0; m < MR; m++)
#pragma unroll
        for (int n = 0; n < NR; n++)
          acc[m][n] = __builtin_amdgcn_mfma_f32_16x16x32_bf16(af[m], bf[n], acc[m][n], 0, 0, 0);
    }
    __syncthreads();
  }
  // epilogue: D row = A-row = (lane>>4)*4+r, D col = B-row = lane&15 (HW-verified r2)
#pragma unroll
  for (int m = 0; m < MR; m++){
#pragma unroll
    for (int n = 0; n < NR; n++){
      int col = col0 + wn * WN + n * 16 + (lane & 15);
      float bsv = bias[col];
      int rbase = row0 + wm * WM + m * 16 + (lane >> 4) * 4;
#pragma unroll
      for (int r = 0; r < 4; r++){
        float v = acc[m][n][r] + bsv;
        if (EPI == 3) v = fmaxf(v, 0.f);
        if (OUTBF) ((unsigned short*)Cout)[(size_t)(rbase + r) * N + col] = f2bf(v);
        else       ((float*)Cout)[(size_t)(rbase + r) * N + col] = v;
      }
    }
  }
}

// ---------------- attention core (MFMA scores, bf16 LDS tile, bf16 P/C) ----------------
__global__ __launch_bounds__(256) void k_attn(const int* __restrict__ nei_idx,
                                              const void* __restrict__ nei_mask,
                                              const int* __restrict__ flagp,
                                              const float* __restrict__ emb,
                                              const unsigned short* __restrict__ Pb,
                                              unsigned short* __restrict__ Cb){
  const int b = blockIdx.x;
  const int tid = threadIdx.x;
  const int w = tid >> 6, lane = tid & 63;
  __shared__ __align__(16) unsigned short Ebf[64 * 256];  // 32 KB, swizzled
  __shared__ __align__(16) unsigned short Pl[9 * 256];    // 4.5 KB, row 8 = zeros
  __shared__ float sc[NH * LN_];
  __shared__ int   nid[LN_];
  __shared__ float mskv[LN_];
  char* eb = (char*)Ebf;
  char* pl = (char*)Pl;

  const int fl = flagp[0];
  const int mf = (fl & 2) ? 2 : ((fl & 1) ? 1 : 0);
  if (tid < LN_){
    nid[tid] = nei_idx[(size_t)b * LN_ + tid];
    bool m;
    if (mf == 1)      m = ((const unsigned char*)nei_mask)[(size_t)b * LN_ + tid] != 0;
    else if (mf == 2) m = ((const float*)nei_mask)[(size_t)b * LN_ + tid] != 0.f;
    else              m = ((const int*)nei_mask)[(size_t)b * LN_ + tid] != 0;
    mskv[tid] = m ? 1.f : 0.f;
  }
  // stage P[b] (bf16, 8 rows x 256) into swizzled LDS; zero pad row 8
  {
    int r = tid >> 5, cb16 = (tid & 31) * 16;
    uint4 v = *(const uint4*)((const char*)Pb + (size_t)b * 4096 + r * 512 + cb16);
    *(uint4*)(pl + ESWZ(r, r * 512 + cb16)) = v;
    if (tid < 64) *(uint2*)(pl + 8 * 512 + tid * 8) = make_uint2(0u, 0u);
  }
  __syncthreads();   // nid ready

  // stage 64 neighbor rows (f32 -> bf16, swizzled), two 8-row register batches
#pragma unroll
  for (int half = 0; half < 2; half++){
    float4 vr[8];
#pragma unroll
    for (int i = 0; i < 8; i++){
      int l = w * 16 + half * 8 + i;
      vr[i] = ((const float4*)(emb + (size_t)nid[l] * D))[lane];
    }
#pragma unroll
    for (int i = 0; i < 8; i++){
      int l = w * 16 + half * 8 + i;
      uint2 p;
      p.x = (unsigned)f2bf(vr[i].x) | ((unsigned)f2bf(vr[i].y) << 16);
      p.y = (unsigned)f2bf(vr[i].z) | ((unsigned)f2bf(vr[i].w) << 16);
      *(uint2*)(eb + ESWZ(l, l * 512 + lane * 8)) = p;
    }
  }
  __syncthreads();

  // scores^T[h, l] via MFMA: A = P rows (8 real + zero pad), B = E rows
  {
    const int hr = lane & 15;
    const int arow = hr < 8 ? hr : 8;
    const int bl = w * 16 + (lane & 15);
    const int koff = (lane >> 4) * 16;
    f32x4 acc = {0.f, 0.f, 0.f, 0.f};
#pragma unroll
    for (int kk = 0; kk < 8; kk++){
      short8 af = *(const short8*)(pl + ESWZ(arow, arow * 512 + kk * 64 + koff));
      short8 bf = *(const short8*)(eb + ESWZ(bl, bl * 512 + kk * 64 + koff));
      acc = __builtin_amdgcn_mfma_f32_16x16x32_bf16(af, bf, acc, 0, 0, 0);
    }
    int l = w * 16 + (lane & 15);
    int hb = (lane >> 4) * 4;
    if (hb < 8){
#pragma unroll
      for (int r = 0; r < 4; r++) sc[(hb + r) * LN_ + l] = acc[r];
    }
  }
  __syncthreads();

  // softmax: 8 h-groups x 32 threads, each thread covers l = j and j+32
  {
    int h = tid >> 5, j = tid & 31;
    float v0 = mskv[j]      > 0.5f ? -INFINITY : sc[h * LN_ + j];
    float v1 = mskv[j + 32] > 0.5f ? -INFINITY : sc[h * LN_ + j + 32];
    float m = fmaxf(v0, v1);
#pragma unroll
    for (int off = 16; off; off >>= 1) m = fmaxf(m, __shfl_xor(m, off, 64));
    float e0 = __expf(v0 - m), e1 = __expf(v1 - m);
    float s = e0 + e1;
#pragma unroll
    for (int off = 16; off; off >>= 1) s += __shfl_xor(s, off, 64);
    float inv = 1.f / s;
    sc[h * LN_ + j]      = e0 * inv;
    sc[h * LN_ + j + 32] = e1 * inv;
  }
  __syncthreads();

  // PV: wave w computes heads {2w, 2w+1}; lane owns d = lane*4..+3; bf16 out
  {
    const int h0 = w * 2, h1 = w * 2 + 1;
    float4 a0 = make_float4(0.f, 0.f, 0.f, 0.f);
    float4 a1 = make_float4(0.f, 0.f, 0.f, 0.f);
#pragma unroll 8
    for (int l = 0; l < 64; l++){
      uint2 raw = *(const uint2*)(eb + ESWZ(l, l * 512 + lane * 8));
      float e0 = __uint_as_float(raw.x << 16);
      float e1 = __uint_as_float(raw.x & 0xFFFF0000u);
      float e2 = __uint_as_float(raw.y << 16);
      float e3 = __uint_as_float(raw.y & 0xFFFF0000u);
      float t0 = sc[h0 * LN_ + l], t1 = sc[h1 * LN_ + l];
      a0.x = fmaf(t0, e0, a0.x); a0.y = fmaf(t0, e1, a0.y);
      a0.z = fmaf(t0, e2, a0.z); a0.w = fmaf(t0, e3, a0.w);
      a1.x = fmaf(t1, e0, a1.x); a1.y = fmaf(t1, e1, a1.y);
      a1.z = fmaf(t1, e2, a1.z); a1.w = fmaf(t1, e3, a1.w);
    }
    uint2 o0, o1;
    o0.x = (unsigned)f2bf(a0.x) | ((unsigned)f2bf(a0.y) << 16);
    o0.y = (unsigned)f2bf(a0.z) | ((unsigned)f2bf(a0.w) << 16);
    o1.x = (unsigned)f2bf(a1.x) | ((unsigned)f2bf(a1.y) << 16);
    o1.y = (unsigned)f2bf(a1.z) | ((unsigned)f2bf(a1.w) << 16);
    *(uint2*)((char*)Cb + (size_t)b * 4096 + h0 * 512 + lane * 8) = o0;
    *(uint2*)((char*)Cb + (size_t)b * 4096 + h1 * 512 + lane * 8) = o1;
  }
}

// ---------------- LayerNorm(out = LN(A+B)), optional bf16 copy ----------------
__global__ __launch_bounds__(256) void k_ln(const float* __restrict__ A,
                                            const float* __restrict__ Bv,
                                            const float* __restrict__ w,
                                            const float* __restrict__ bi,
                                            float* __restrict__ out,
                                            unsigned short* __restrict__ outb){
  const int row = blockIdx.x, tid = threadIdx.x;
  const int wv = tid >> 6, lane = tid & 63;
  __shared__ float red[8];
  float v = A[(size_t)row * D + tid] + Bv[(size_t)row * D + tid];
  float s = wave_sum(v);
  if (lane == 0) red[wv] = s;
  __syncthreads();
  float mu = (red[0] + red[1] + red[2] + red[3]) * (1.f / D);
  float d = v - mu;
  float s2 = wave_sum(d * d);
  if (lane == 0) red[4 + wv] = s2;
  __syncthreads();
  float var = (red[4] + red[5] + red[6] + red[7]) * (1.f / D);
  float res = d * rsqrtf(var + EPSV) * w[tid] + bi[tid];
  out[(size_t)row * D + tid] = res;
  if (outb) outb[(size_t)row * D + tid] = f2bf(res);
}

// ---------------- launch ----------------
extern "C" void kernel_launch(void* const* d_in, const int* in_sizes, int n_in,
                              void* d_out, int out_size, void* d_ws, size_t ws_size,
                              hipStream_t stream){
  (void)in_sizes; (void)n_in; (void)out_size; (void)ws_size;
  const int*   batch    = (const int*)d_in[0];
  const int*   nei_idx  = (const int*)d_in[1];
  const void*  nei_mask = d_in[2];
  const float* emb      = (const float*)d_in[3];
  const float* Wq = (const float*)d_in[4];  const float* bq = (const float*)d_in[5];
  const float* Wk = (const float*)d_in[6];  /* bk dropped: softmax-invariant */
  const float* Wv = (const float*)d_in[8];  const float* bv = (const float*)d_in[9];
  const float* Wo = (const float*)d_in[10]; const float* bo = (const float*)d_in[11];
  const float* W1 = (const float*)d_in[12]; const float* b1 = (const float*)d_in[13];
  const float* W2 = (const float*)d_in[14]; const float* b2 = (const float*)d_in[15];
  const float* ln1w = (const float*)d_in[16]; const float* ln1b = (const float*)d_in[17];
  const float* ln2w = (const float*)d_in[18]; const float* ln2b = (const float*)d_in[19];

  float* ws = (float*)d_ws;
  // 4-MiB slots
  float* X  = ws;                        // slot 0
  float* Y  = ws + (size_t)1 * 1048576;  // slot 1
  float* S  = ws + (size_t)2 * 1048576;  // slot 2
  float* F  = ws + (size_t)3 * 1048576;  // slot 3
  unsigned short* Pbf = (unsigned short*)(ws + (size_t)4 * 1048576);  // slots 4-7 [4096][2048]
  unsigned short* Cb  = Pbf;             // alias: attn block b reads P[b] fully before writing C[b]
  unsigned short* Sb  = (unsigned short*)(ws + (size_t)8 * 1048576);  // slot 8 (2 MB used)
  unsigned short* HHb = (unsigned short*)(ws + (size_t)9 * 1048576);  // slots 9-10 (8 MB)
  unsigned short* Xb  = (unsigned short*)(ws + (size_t)11 * 1048576); // slot 11 (2 MB used)
  char* wb = (char*)(ws + (size_t)12 * 1048576);
  unsigned short* W1t = (unsigned short*)(wb);                        // 512 KiB
  unsigned short* W2t = (unsigned short*)(wb + (512u << 10));         // 512 KiB
  unsigned short* Mt  = (unsigned short*)(wb + (1024u << 10));        // 1 MiB
  unsigned short* Gt  = (unsigned short*)(wb + (2048u << 10));        // 1 MiB
  float* pbv  = (float*)(wb + (3072u << 10));                         // 8 KiB
  float* bo2  = (float*)(wb + (3072u << 10) + 8192);                  // 1 KiB
  int*   flags = (int*)(wb + (3072u << 10) + 16384);
  float* out = (float*)d_out;

  hipMemsetAsync(flags, 0, 4, stream);
  k_prep<<<1665, 256, 0, stream>>>(Wq, Wk, Wv, Wo, W1, W2, bq, bv, bo,
                                   batch, emb, (const unsigned int*)nei_mask,
                                   W1t, W2t, Mt, Gt, pbv, bo2, X, Xb, flags);
  // P = Xb @ Mt^T + pb  [bf16 out], N=2048
  k_mgemm<128, 64, 2, true><<<dim3(2048 / 64, BQ / 128), 256, 0, stream>>>(Xb, Mt, pbv, Pbf, BQ, 2048, 256);
  k_attn<<<BQ, 256, 0, stream>>>(nei_idx, nei_mask, flags, emb, Pbf, Cb);
  // Y = Cb @ Gt^T + bo2  [f32 out], K=2048
  k_mgemm<64, 64, 2, false><<<dim3(D / 64, BQ / 64), 256, 0, stream>>>(Cb, Gt, bo2, Y, BQ, D, 2048);
  k_ln<<<BQ, 256, 0, stream>>>(X, Y, ln1w, ln1b, S, Sb);
  // HH = relu(S@W1 + b1)  [bf16 out]
  k_mgemm<128, 64, 3, true><<<dim3(DFF / 64, BQ / 128), 256, 0, stream>>>(Sb, W1t, b1, HHb, BQ, DFF, 256);
  // F = relu(HH@W2 + b2)  [f32 out]
  k_mgemm<64, 64, 3, false><<<dim3(D / 64, BQ / 64), 256, 0, stream>>>(HHb, W2t, b2, F, BQ, D, DFF);
  k_ln<<<BQ, 256, 0, stream>>>(S, F, ln2w, ln2b, out, nullptr);
}